// Round 10
// baseline (345.105 us; speedup 1.0000x reference)
//
#include <hip/hip_runtime.h>
#include <math.h>

#define NIN 91392        // 17*21*16*16
#define DIN 8
#define DOUT 16
#define BATCH 16
#define KCH 4            // chunks of 8 n per tile -> 32 contiguous n
#define NTILE 2856       // 2856 * 32 = 91392 n
#define TPB 512          // 8 waves; wave w owns batches {2w, 2w+1}

// Pass kernel: recompute u_hat[j,n,o] = sum_i x[b,n,i]*W[j,n,i,o] on the fly.
// Phase A (staging): block cooperatively copies its tile into LDS:
//   ldsW4[p]: p = r*32 + slot', r = j*32+nn (64 rows), content W(r, slot'^(r&7))
//   (XOR swizzle on the LDS-write side -> bank-floor reads; T2 recipe)
//   ldsX4[p]: p = b*64 + nn*2 + h, linear copy of x tile.
//   Per wave: 6 independent 1KB loads in flight -> BW-bound, not latency-bound
//   (R9 lesson: fused load+compute at 52 VGPR serializes every load).
// Phase B (compute): R9's verified math, all operands from LDS.
// lane = (g:3)(j:1)(og:2). PASS 0: sum_n u. PASS>0: c = sigmoid(sgn*d).
template<int PASS>
__global__ __launch_bounds__(TPB) void caps_pass(
    const float* __restrict__ x, const float* __restrict__ W,
    const float* __restrict__ vin, float* __restrict__ part)
{
    const int t = threadIdx.x;
    const int lane = t & 63;
    const int wave = t >> 6;          // 0..7
    const int og = lane & 3;          // o-group of 4
    const int j  = (lane >> 2) & 1;   // capsule
    const int g  = lane >> 3;         // n within chunk, 0..7
    const int b0 = wave * 2;
    const int grid = gridDim.x;

    __shared__ __align__(16) float4 ldsW4[2048];   // 32 KB
    __shared__ __align__(16) float4 ldsX4[1024];   // 16 KB

    const float sgn = j ? -1.f : 1.f;

    float4 vin4[2];
    if (PASS > 0) {
        #pragma unroll
        for (int b = 0; b < 2; ++b) {
            float4 v = *(const float4*)(vin + (b0 + b) * 32 + j * 16 + og * 4);
            vin4[b] = make_float4(sgn * v.x, sgn * v.y, sgn * v.z, sgn * v.w);
        }
    }

    float4 acc0 = make_float4(0.f, 0.f, 0.f, 0.f);
    float4 acc1 = make_float4(0.f, 0.f, 0.f, 0.f);

    const float4* Wf4 = (const float4*)W;
    const float4* Xf4 = (const float4*)x;

    for (int tile = blockIdx.x; tile < NTILE; tile += grid) {
        // ---- Phase A: stage W (2048 f4) + x (1024 f4) ----
        #pragma unroll
        for (int rr = 0; rr < 4; ++rr) {
            const int p = rr * 512 + t;       // linear source index
            const int r = p >> 5;             // row = j*32 + nn
            const int slot = p & 31;
            const size_t gidx = (size_t)(r >> 5) * (NIN * 32)
                              + (size_t)tile * 1024 + (r & 31) * 32 + slot;
            ldsW4[(r << 5) | (slot ^ (r & 7))] = Wf4[gidx];
        }
        #pragma unroll
        for (int rr = 0; rr < 2; ++rr) {
            const int p = rr * 512 + t;
            ldsX4[p] = Xf4[(size_t)(p >> 6) * (NIN * 2)
                         + (size_t)tile * 64 + (p & 63)];
        }
        __syncthreads();

        // ---- Phase B: compute from LDS ----
        #pragma unroll
        for (int k = 0; k < KCH; ++k) {
            const int xb = (k * 8 + g) * 2;
            const float4 xa  = ldsX4[(b0 + 0) * 64 + xb];
            const float4 xc  = ldsX4[(b0 + 0) * 64 + xb + 1];
            const float4 ya  = ldsX4[(b0 + 1) * 64 + xb];
            const float4 yc  = ldsX4[(b0 + 1) * 64 + xb + 1];
            const float x0[8] = {xa.x, xa.y, xa.z, xa.w, xc.x, xc.y, xc.z, xc.w};
            const float x1[8] = {ya.x, ya.y, ya.z, ya.w, yc.x, yc.y, yc.z, yc.w};

            const int wbase = j * 1024 + k * 256 + g * 32;   // r*32
            float4 u0 = make_float4(0.f, 0.f, 0.f, 0.f);
            float4 u1 = make_float4(0.f, 0.f, 0.f, 0.f);
            #pragma unroll
            for (int i = 0; i < DIN; ++i) {
                const float4 w4 = ldsW4[wbase + (((i << 2) | og) ^ g)];
                u0.x += x0[i] * w4.x;  u0.y += x0[i] * w4.y;
                u0.z += x0[i] * w4.z;  u0.w += x0[i] * w4.w;
                u1.x += x1[i] * w4.x;  u1.y += x1[i] * w4.y;
                u1.z += x1[i] * w4.z;  u1.w += x1[i] * w4.w;
            }

            if (PASS == 0) {
                acc0.x += u0.x; acc0.y += u0.y; acc0.z += u0.z; acc0.w += u0.w;
                acc1.x += u1.x; acc1.y += u1.y; acc1.z += u1.z; acc1.w += u1.w;
            } else {
                float m0 = vin4[0].x*u0.x + vin4[0].y*u0.y + vin4[0].z*u0.z + vin4[0].w*u0.w;
                float m1 = vin4[1].x*u1.x + vin4[1].y*u1.y + vin4[1].z*u1.z + vin4[1].w*u1.w;
                m0 += __shfl_xor(m0, 1);  m1 += __shfl_xor(m1, 1);
                m0 += __shfl_xor(m0, 2);  m1 += __shfl_xor(m1, 2);
                m0 += __shfl_xor(m0, 4);  m1 += __shfl_xor(m1, 4);
                const float c0 = __builtin_amdgcn_rcpf(1.f + __expf(-sgn * m0));
                const float c1 = __builtin_amdgcn_rcpf(1.f + __expf(-sgn * m1));
                acc0.x += c0 * u0.x; acc0.y += c0 * u0.y;
                acc0.z += c0 * u0.z; acc0.w += c0 * u0.w;
                acc1.x += c1 * u1.x; acc1.y += c1 * u1.y;
                acc1.z += c1 * u1.z; acc1.w += c1 * u1.w;
            }
        }
        __syncthreads();   // all reads done before next tile's restage
    }

    // g-reduction (bits 3..5), pure shuffles
    #pragma unroll
    for (int s = 8; s <= 32; s <<= 1) {
        acc0.x += __shfl_xor(acc0.x, s); acc0.y += __shfl_xor(acc0.y, s);
        acc0.z += __shfl_xor(acc0.z, s); acc0.w += __shfl_xor(acc0.w, s);
        acc1.x += __shfl_xor(acc1.x, s); acc1.y += __shfl_xor(acc1.y, s);
        acc1.z += __shfl_xor(acc1.z, s); acc1.w += __shfl_xor(acc1.w, s);
    }
    if (g == 0) {
        const int bid = blockIdx.x;
        // column-major partials: part[col][bid], col = b*32 + j*16 + o
        const size_t c0 = ((size_t)(b0 + 0) * 32 + j * 16 + og * 4) * grid + bid;
        const size_t c1 = ((size_t)(b0 + 1) * 32 + j * 16 + og * 4) * grid + bid;
        part[c0 + 0 * (size_t)grid] = acc0.x;  part[c0 + 1 * (size_t)grid] = acc0.y;
        part[c0 + 2 * (size_t)grid] = acc0.z;  part[c0 + 3 * (size_t)grid] = acc0.w;
        part[c1 + 0 * (size_t)grid] = acc1.x;  part[c1 + 1 * (size_t)grid] = acc1.y;
        part[c1 + 2 * (size_t)grid] = acc1.z;  part[c1 + 3 * (size_t)grid] = acc1.w;
    }
}

// Reduce partials -> s[b,j,o], squash -> v. 32 blocks = one per (b,j).
// PASS 0: scale 0.5 (uniform softmax), write v0
// PASS 1: write v0+v1 (logits linear in accumulated v)
// PASS 2: write final v
template<int PASS>
__global__ __launch_bounds__(256) void caps_reduce(
    const float* __restrict__ part, const float* __restrict__ vprev,
    float* __restrict__ vout, int gridA)
{
    const int blk = blockIdx.x;   // b*2 + j
    const int b = blk >> 1, j = blk & 1;
    const int t = threadIdx.x;
    const int o = t & 15;
    const int ch = t >> 4;
    const size_t base = ((size_t)b * 32 + j * 16 + o) * gridA;
    float s = 0.f;
    for (int g = ch; g < gridA; g += 16) s += part[base + g];
    __shared__ float red[256];
    red[t] = s;
    __syncthreads();
    if (t < 16) {
        float sv = 0.f;
        #pragma unroll
        for (int c = 0; c < 16; ++c) sv += red[c * 16 + t];
        if (PASS == 0) sv *= 0.5f;
        float sq = sv * sv;
        sq += __shfl_xor(sq, 1);
        sq += __shfl_xor(sq, 2);
        sq += __shfl_xor(sq, 4);
        sq += __shfl_xor(sq, 8);
        const float sn = sq;
        float v = sv * sn / ((1.f + sn) * sqrtf(sn + 1e-7f));
        if (PASS == 1) v += vprev[b * 32 + j * 16 + o];
        vout[b * 32 + j * 16 + o] = v;
    }
}

extern "C" void kernel_launch(void* const* d_in, const int* in_sizes, int n_in,
                              void* d_out, int out_size, void* d_ws, size_t ws_size,
                              hipStream_t stream) {
    const float* x = (const float*)d_in[0];
    const float* W = (const float*)d_in[1];
    float* out = (float*)d_out;

    // grid clamped to workspace (part = 512*GRID floats); blocks tile-stride
    size_t maxg = (ws_size - 4096) / (512 * sizeof(float));
    int GRID = (int)(maxg < NTILE ? maxg : NTILE);
    if (GRID < 1) GRID = 1;

    float* part = (float*)d_ws;
    float* v0   = part + (size_t)512 * GRID;
    float* vsum = v0 + 512;

    caps_pass<0><<<GRID, TPB, 0, stream>>>(x, W, nullptr, part);
    caps_reduce<0><<<32, 256, 0, stream>>>(part, nullptr, v0, GRID);
    caps_pass<1><<<GRID, TPB, 0, stream>>>(x, W, v0, part);
    caps_reduce<1><<<32, 256, 0, stream>>>(part, v0, vsum, GRID);
    caps_pass<2><<<GRID, TPB, 0, stream>>>(x, W, vsum, part);
    caps_reduce<2><<<32, 256, 0, stream>>>(part, nullptr, out, GRID);
}

// Round 11
// 173.926 us; speedup vs baseline: 1.9842x; 1.9842x over previous
//
#include <hip/hip_runtime.h>
#include <math.h>

#define NIN 91392        // 17*21*16*16
#define DIN 8
#define DOUT 16
#define NCHUNK (NIN / 8) // 11424 chunks of 8 n
#define GRID_P 1024      // persistent: 4 blocks/CU x 256 CUs -> 32 waves/CU
#define TPB 512          // 8 waves; wave w owns batches {2w, 2w+1}

// Pass kernel: recompute u_hat[j,n,o] = sum_i x[b,n,i]*W[j,n,i,o] on the fly.
// R9's verified 52-VGPR no-LDS compute core, made PERSISTENT: 1024 blocks
// all resident simultaneously (R9's 1428x8w = 1.4 ragged rounds -> 35% occ;
// occupancy<->BW is the strongest measured correlation across R5-R10).
// lane = (g:3)(j:1)(og:2); wave owns 2 batches; chunk-stride loop.
// PASS 0: s0 partial = sum_n u. PASS>0: c = sigmoid(sgn*d), 3-shuffle d.
template<int PASS>
__global__ __launch_bounds__(TPB) void caps_pass(
    const float* __restrict__ x, const float* __restrict__ W,
    const float* __restrict__ vin, float* __restrict__ part, int grid)
{
    const int t = threadIdx.x;
    const int lane = t & 63;
    const int wave = t >> 6;          // 0..7
    const int og = lane & 3;          // o-group: o = og*4..og*4+3
    const int j  = (lane >> 2) & 1;   // capsule
    const int g  = lane >> 3;         // n within chunk, 0..7
    const int bid = blockIdx.x;
    const int b0 = wave * 2;

    const float sgn = j ? -1.f : 1.f;

    float4 vin4[2];
    if (PASS > 0) {
        #pragma unroll
        for (int b = 0; b < 2; ++b) {
            float4 v = *(const float4*)(vin + (b0 + b) * 32 + j * 16 + og * 4);
            vin4[b] = make_float4(sgn * v.x, sgn * v.y, sgn * v.z, sgn * v.w);
        }
    }

    float4 acc0 = make_float4(0.f, 0.f, 0.f, 0.f);
    float4 acc1 = make_float4(0.f, 0.f, 0.f, 0.f);

    for (int c = bid; c < NCHUNK; c += grid) {
        const int n = c * 8 + g;
        const float* wp  = W + ((size_t)j * NIN + n) * (DIN * DOUT) + og * 4;
        const float* xp0 = x + ((size_t)(b0 + 0) * NIN + n) * DIN;
        const float* xp1 = x + ((size_t)(b0 + 1) * NIN + n) * DIN;

        // x[b][n][0..7] into scalar regs (constant indices -> VGPRs)
        float x0[DIN], x1[DIN];
        {
            const float4 a = *(const float4*)(xp0);
            const float4 c4 = *(const float4*)(xp0 + 4);
            x0[0]=a.x; x0[1]=a.y; x0[2]=a.z; x0[3]=a.w;
            x0[4]=c4.x; x0[5]=c4.y; x0[6]=c4.z; x0[7]=c4.w;
            const float4 a1 = *(const float4*)(xp1);
            const float4 c1 = *(const float4*)(xp1 + 4);
            x1[0]=a1.x; x1[1]=a1.y; x1[2]=a1.z; x1[3]=a1.w;
            x1[4]=c1.x; x1[5]=c1.y; x1[6]=c1.z; x1[7]=c1.w;
        }

        float4 u0 = make_float4(0.f, 0.f, 0.f, 0.f);
        float4 u1 = make_float4(0.f, 0.f, 0.f, 0.f);
        #pragma unroll
        for (int i = 0; i < DIN; ++i) {
            const float4 w4 = *(const float4*)(wp + i * DOUT);  // 64B-step imm offsets
            u0.x += x0[i] * w4.x;  u0.y += x0[i] * w4.y;
            u0.z += x0[i] * w4.z;  u0.w += x0[i] * w4.w;
            u1.x += x1[i] * w4.x;  u1.y += x1[i] * w4.y;
            u1.z += x1[i] * w4.z;  u1.w += x1[i] * w4.w;
        }

        if (PASS == 0) {
            acc0.x += u0.x; acc0.y += u0.y; acc0.z += u0.z; acc0.w += u0.w;
            acc1.x += u1.x; acc1.y += u1.y; acc1.z += u1.z; acc1.w += u1.w;
        } else {
            // d = b_0 - b_1: per-lane partial sgn*(v.u over own 4 o), then
            // butterfly over (og,j) lanes = bits 0..2
            float m0 = vin4[0].x*u0.x + vin4[0].y*u0.y + vin4[0].z*u0.z + vin4[0].w*u0.w;
            float m1 = vin4[1].x*u1.x + vin4[1].y*u1.y + vin4[1].z*u1.z + vin4[1].w*u1.w;
            m0 += __shfl_xor(m0, 1);  m1 += __shfl_xor(m1, 1);
            m0 += __shfl_xor(m0, 2);  m1 += __shfl_xor(m1, 2);
            m0 += __shfl_xor(m0, 4);  m1 += __shfl_xor(m1, 4);
            const float c0 = __builtin_amdgcn_rcpf(1.f + __expf(-sgn * m0));
            const float c1 = __builtin_amdgcn_rcpf(1.f + __expf(-sgn * m1));
            acc0.x += c0 * u0.x; acc0.y += c0 * u0.y;
            acc0.z += c0 * u0.z; acc0.w += c0 * u0.w;
            acc1.x += c1 * u1.x; acc1.y += c1 * u1.y;
            acc1.z += c1 * u1.z; acc1.w += c1 * u1.w;
        }
    }

    // g-reduction (bits 3..5), pure shuffles, no LDS
    #pragma unroll
    for (int s = 8; s <= 32; s <<= 1) {
        acc0.x += __shfl_xor(acc0.x, s); acc0.y += __shfl_xor(acc0.y, s);
        acc0.z += __shfl_xor(acc0.z, s); acc0.w += __shfl_xor(acc0.w, s);
        acc1.x += __shfl_xor(acc1.x, s); acc1.y += __shfl_xor(acc1.y, s);
        acc1.z += __shfl_xor(acc1.z, s); acc1.w += __shfl_xor(acc1.w, s);
    }
    if (g == 0) {
        // column-major partials: part[col][bid], col = b*32 + j*16 + o
        const size_t c0 = ((size_t)(b0 + 0) * 32 + j * 16 + og * 4) * grid + bid;
        const size_t c1 = ((size_t)(b0 + 1) * 32 + j * 16 + og * 4) * grid + bid;
        part[c0 + 0 * (size_t)grid] = acc0.x;  part[c0 + 1 * (size_t)grid] = acc0.y;
        part[c0 + 2 * (size_t)grid] = acc0.z;  part[c0 + 3 * (size_t)grid] = acc0.w;
        part[c1 + 0 * (size_t)grid] = acc1.x;  part[c1 + 1 * (size_t)grid] = acc1.y;
        part[c1 + 2 * (size_t)grid] = acc1.z;  part[c1 + 3 * (size_t)grid] = acc1.w;
    }
}

// Reduce partials -> s[b,j,o], squash -> v. 32 blocks = one per (b,j).
// PASS 0: scale 0.5 (uniform softmax), write v0
// PASS 1: write v0+v1 (logits linear in accumulated v)
// PASS 2: write final v
template<int PASS>
__global__ __launch_bounds__(256) void caps_reduce(
    const float* __restrict__ part, const float* __restrict__ vprev,
    float* __restrict__ vout, int gridA)
{
    const int blk = blockIdx.x;   // b*2 + j
    const int b = blk >> 1, j = blk & 1;
    const int t = threadIdx.x;
    const int o = t & 15;
    const int ch = t >> 4;
    const size_t base = ((size_t)b * 32 + j * 16 + o) * gridA;
    float s = 0.f;
    for (int g = ch; g < gridA; g += 16) s += part[base + g];
    __shared__ float red[256];
    red[t] = s;
    __syncthreads();
    if (t < 16) {
        float sv = 0.f;
        #pragma unroll
        for (int c = 0; c < 16; ++c) sv += red[c * 16 + t];
        if (PASS == 0) sv *= 0.5f;
        float sq = sv * sv;
        sq += __shfl_xor(sq, 1);
        sq += __shfl_xor(sq, 2);
        sq += __shfl_xor(sq, 4);
        sq += __shfl_xor(sq, 8);
        const float sn = sq;
        float v = sv * sn / ((1.f + sn) * sqrtf(sn + 1e-7f));
        if (PASS == 1) v += vprev[b * 32 + j * 16 + o];
        vout[b * 32 + j * 16 + o] = v;
    }
}

extern "C" void kernel_launch(void* const* d_in, const int* in_sizes, int n_in,
                              void* d_out, int out_size, void* d_ws, size_t ws_size,
                              hipStream_t stream) {
    const float* x = (const float*)d_in[0];
    const float* W = (const float*)d_in[1];
    float* out = (float*)d_out;

    // persistent grid; clamp to workspace (part = 512*GRID floats)
    size_t maxg = (ws_size - 4096) / (512 * sizeof(float));
    int GRID = (int)(maxg < GRID_P ? maxg : GRID_P);
    if (GRID < 1) GRID = 1;

    float* part = (float*)d_ws;                       // 512*GRID floats (2 MB)
    float* v0   = part + (size_t)512 * GRID;          // 512
    float* vsum = v0 + 512;                           // 512

    caps_pass<0><<<GRID, TPB, 0, stream>>>(x, W, nullptr, part, GRID);
    caps_reduce<0><<<32, 256, 0, stream>>>(part, nullptr, v0, GRID);
    caps_pass<1><<<GRID, TPB, 0, stream>>>(x, W, v0, part, GRID);
    caps_reduce<1><<<32, 256, 0, stream>>>(part, v0, vsum, GRID);
    caps_pass<2><<<GRID, TPB, 0, stream>>>(x, W, vsum, part, GRID);
    caps_reduce<2><<<32, 256, 0, stream>>>(part, nullptr, out, GRID);
}